// Round 1
// baseline (14097.818 us; speedup 1.0000x reference)
//
#include <hip/hip_runtime.h>
#include <stdint.h>

// Neural-ODE actor: y' = MLP(y), y(0)=[x|z], integrate t:0->1 with fixed RK4.
// NSTEP=32 (128 field evals). bf16 MFMA GEMMs, fp32 state + RK accumulation.
// COMB=96 padded to KP=128 so all GEMM dims are multiples of the 128-tile.

#define NSTEP 32

static constexpr int Bsz   = 16384;
static constexpr int IN_D  = 64;
static constexpr int OUT_D = 32;
static constexpr int CMB   = 96;   // IN_D + OUT_D
static constexpr int KP    = 128;  // padded CMB
static constexpr int HID   = 1024;

typedef __bf16 bf16x8 __attribute__((ext_vector_type(8)));
typedef float  f32x4  __attribute__((ext_vector_type(4)));

__device__ __forceinline__ uint16_t f2bf(float f) {
  uint32_t u = __float_as_uint(f);
  u += 0x7fffu + ((u >> 16) & 1u);   // RNE; inputs are finite
  return (uint16_t)(u >> 16);
}

// async global->LDS, 16B per lane. LDS dest is wave-uniform base + lane*16.
__device__ __forceinline__ void gl2lds16(const uint16_t* g, uint16_t* l) {
  typedef const __attribute__((address_space(1))) uint16_t gq_t;
  typedef __attribute__((address_space(3))) uint16_t ls_t;
  __builtin_amdgcn_global_load_lds((gq_t*)(uintptr_t)g, (ls_t*)(uintptr_t)l, 16, 0, 0);
}

// C[M,N] = act(A[M,K] @ Wt[N,K]^T + bias). A row-major (ld=K), Wt row-major [N][K].
// 128x128 tile, 4 waves, each wave 64x64 via 4x4 grid of 16x16x32 bf16 MFMAs.
// RELU_BF16: relu + bf16 output (ld=N); else raw f32 output (ld=N).
template <bool RELU_BF16>
__global__ __launch_bounds__(256) void gemm_kernel(
    const uint16_t* __restrict__ A, const uint16_t* __restrict__ Bt,
    void* __restrict__ Cout, const float* __restrict__ bias,
    int M, int N, int K, int bias_valid)
{
  __shared__ uint16_t As[128 * 32];
  __shared__ uint16_t Bs[128 * 32];

  const int tid  = threadIdx.x;
  const int wave = tid >> 6;
  const int lane = tid & 63;
  const int m0 = blockIdx.y * 128;
  const int n0 = blockIdx.x * 128;
  const int wm = (wave & 1) * 64;
  const int wn = (wave >> 1) * 64;

  // staging: each wave loads 2x (64 lanes x 16B) chunks for As and Bs.
  // chunk covers 16 rows x 32 k (row-major [128][32] bf16 in LDS).
  const int srow = wave * 32 + (lane >> 2);
  const int scol = (lane & 3) * 8;

  const uint16_t* gA0 = A  + (size_t)(m0 + srow) * K + scol;
  const uint16_t* gA1 = gA0 + (size_t)16 * K;
  const uint16_t* gB0 = Bt + (size_t)(n0 + srow) * K + scol;
  const uint16_t* gB1 = gB0 + (size_t)16 * K;

  uint16_t* lA0 = As + wave * 1024;
  uint16_t* lA1 = lA0 + 512;
  uint16_t* lB0 = Bs + wave * 1024;
  uint16_t* lB1 = lB0 + 512;

  f32x4 acc[4][4];
  const f32x4 z4 = {0.0f, 0.0f, 0.0f, 0.0f};
#pragma unroll
  for (int i = 0; i < 4; ++i)
#pragma unroll
    for (int j = 0; j < 4; ++j) acc[i][j] = z4;

  // A-frag: A[m=lane&15][k=(lane>>4)*8+j]; B-frag mirrors with n=lane&15.
  const int afo = (wm + (lane & 15)) * 32 + (lane >> 4) * 8;
  const int bfo = (wn + (lane & 15)) * 32 + (lane >> 4) * 8;

  for (int k0 = 0; k0 < K; k0 += 32) {
    gl2lds16(gA0 + k0, lA0);
    gl2lds16(gA1 + k0, lA1);
    gl2lds16(gB0 + k0, lB0);
    gl2lds16(gB1 + k0, lB1);
    __syncthreads();   // drains vmcnt (async LDS writes) + lgkm

    bf16x8 af[4], bf[4];
#pragma unroll
    for (int i = 0; i < 4; ++i) {
      af[i] = *(const bf16x8*)(As + afo + i * 16 * 32);
      bf[i] = *(const bf16x8*)(Bs + bfo + i * 16 * 32);
    }
#pragma unroll
    for (int i = 0; i < 4; ++i)
#pragma unroll
      for (int j = 0; j < 4; ++j)
        acc[i][j] = __builtin_amdgcn_mfma_f32_16x16x32_bf16(af[i], bf[j], acc[i][j], 0, 0, 0);
    __syncthreads();
  }

  // epilogue: C/D layout col=lane&15, row=(lane>>4)*4+reg
  const int colb = n0 + wn + (lane & 15);
  const int rowb = m0 + wm + ((lane >> 4) << 2);
#pragma unroll
  for (int j = 0; j < 4; ++j) {
    const int c = colb + j * 16;
    const float bv = (c < bias_valid) ? bias[c] : 0.0f;
#pragma unroll
    for (int i = 0; i < 4; ++i) {
#pragma unroll
      for (int r = 0; r < 4; ++r) {
        const int row = rowb + i * 16 + r;
        float v = acc[i][j][r] + bv;
        if (RELU_BF16) {
          v = fmaxf(v, 0.0f);
          ((uint16_t*)Cout)[(size_t)row * N + c] = f2bf(v);
        } else {
          ((float*)Cout)[(size_t)row * N + c] = v;
        }
      }
    }
  }
}

// Wt[n*Kp + k] = bf16(W[k*N + n]) with zero padding (K->Kp rows, N->Np cols).
__global__ void wt_kernel(const float* __restrict__ W, uint16_t* __restrict__ Wt,
                          int K, int N, int Kp, int Np)
{
  int idx = blockIdx.x * blockDim.x + threadIdx.x;
  if (idx >= Np * Kp) return;
  int n = idx / Kp, k = idx - n * Kp;
  float v = (k < K && n < N) ? W[(size_t)k * N + n] : 0.0f;
  Wt[idx] = f2bf(v);
}

// y(0) = [x|z]; ain = bf16(y) padded to KP with zeros.
__global__ void init_k(const float* __restrict__ x, const float* __restrict__ z,
                       float* __restrict__ y, uint16_t* __restrict__ ain)
{
  int i = blockIdx.x * blockDim.x + threadIdx.x;
  if (i >= Bsz * KP) return;
  int row = i >> 7, col = i & 127;
  float v = 0.0f;
  if (col < IN_D) v = x[(size_t)row * IN_D + col];
  else if (col < CMB) v = z[(size_t)row * OUT_D + (col - IN_D)];
  ain[i] = f2bf(v);
  if (col < CMB) y[(size_t)row * CMB + col] = v;
}

// after k1..k3: kacc (+)= wk*k ; ain = bf16(y + cc*k)
__global__ void comb_mid(const float* __restrict__ kc, float* __restrict__ kacc,
                         const float* __restrict__ y, uint16_t* __restrict__ ain,
                         float wk, float cc, int first)
{
  int i = blockIdx.x * blockDim.x + threadIdx.x;
  if (i >= Bsz * CMB) return;
  int row = i / CMB, col = i - row * CMB;
  float kv = kc[(size_t)row * KP + col];
  float ka = first ? (wk * kv) : (kacc[i] + wk * kv);
  kacc[i] = ka;
  ain[(size_t)row * KP + col] = f2bf(y[i] + cc * kv);
}

// after k4: y += kacc + wk*k ; ain = bf16(y)
__global__ void comb_fin(const float* __restrict__ kc, const float* __restrict__ kacc,
                         float* __restrict__ y, uint16_t* __restrict__ ain, float wk)
{
  int i = blockIdx.x * blockDim.x + threadIdx.x;
  if (i >= Bsz * CMB) return;
  int row = i / CMB, col = i - row * CMB;
  float yn = y[i] + kacc[i] + wk * kc[(size_t)row * KP + col];
  y[i] = yn;
  ain[(size_t)row * KP + col] = f2bf(yn);
}

__global__ void fin_k(const float* __restrict__ y, const float* __restrict__ lstd,
                      float* __restrict__ out)
{
  int i = blockIdx.x * blockDim.x + threadIdx.x;
  if (i >= Bsz * OUT_D) return;
  int row = i >> 5, col = i & 31;
  out[i] = y[(size_t)row * CMB + IN_D + col];
  out[(size_t)Bsz * OUT_D + i] = expf(lstd[col]);
}

extern "C" void kernel_launch(void* const* d_in, const int* in_sizes, int n_in,
                              void* d_out, int out_size, void* d_ws, size_t ws_size,
                              hipStream_t stream) {
  const float* x    = (const float*)d_in[0];
  const float* z    = (const float*)d_in[1];
  const float* W1   = (const float*)d_in[2];
  const float* b1   = (const float*)d_in[3];
  const float* W2   = (const float*)d_in[4];
  const float* b2   = (const float*)d_in[5];
  const float* W3   = (const float*)d_in[6];
  const float* b3   = (const float*)d_in[7];
  const float* lstd = (const float*)d_in[8];
  float* out = (float*)d_out;

  char* p = (char*)d_ws;
  auto alloc = [&](size_t bytes) {
    char* r = p;
    p += (bytes + 255) & ~(size_t)255;
    return r;
  };
  uint16_t* W1t  = (uint16_t*)alloc((size_t)HID * KP * 2);
  uint16_t* W2t  = (uint16_t*)alloc((size_t)HID * HID * 2);
  uint16_t* W3t  = (uint16_t*)alloc((size_t)KP * HID * 2);
  float*    y    = (float*)alloc((size_t)Bsz * CMB * 4);
  float*    kacc = (float*)alloc((size_t)Bsz * CMB * 4);
  float*    kcur = (float*)alloc((size_t)Bsz * KP * 4);
  uint16_t* ain  = (uint16_t*)alloc((size_t)Bsz * KP * 2);
  uint16_t* h1   = (uint16_t*)alloc((size_t)Bsz * HID * 2);
  uint16_t* h2   = (uint16_t*)alloc((size_t)Bsz * HID * 2);
  (void)ws_size; (void)in_sizes; (void)n_in; (void)out_size;

  // weight transpose+cast (fresh every launch; ws is re-poisoned by harness)
  wt_kernel<<<(HID * KP + 255) / 256, 256, 0, stream>>>(W1, W1t, CMB, HID, KP, HID);
  wt_kernel<<<(HID * HID + 255) / 256, 256, 0, stream>>>(W2, W2t, HID, HID, HID, HID);
  wt_kernel<<<(KP * HID + 255) / 256, 256, 0, stream>>>(W3, W3t, HID, CMB, HID, KP);

  init_k<<<(Bsz * KP + 255) / 256, 256, 0, stream>>>(x, z, y, ain);

  const float h = 1.0f / (float)NSTEP;
  dim3 blk(256);
  dim3 g12(HID / 128, Bsz / 128);
  dim3 g3(KP / 128, Bsz / 128);
  dim3 gcomb((Bsz * CMB + 255) / 256);

  for (int s = 0; s < NSTEP; ++s) {
    // k1
    gemm_kernel<true ><<<g12, blk, 0, stream>>>(ain, W1t, h1, b1, Bsz, HID, KP, HID);
    gemm_kernel<true ><<<g12, blk, 0, stream>>>(h1, W2t, h2, b2, Bsz, HID, HID, HID);
    gemm_kernel<false><<<g3,  blk, 0, stream>>>(h2, W3t, kcur, b3, Bsz, KP, HID, CMB);
    comb_mid<<<gcomb, blk, 0, stream>>>(kcur, kacc, y, ain, h / 6.0f, h / 2.0f, 1);
    // k2
    gemm_kernel<true ><<<g12, blk, 0, stream>>>(ain, W1t, h1, b1, Bsz, HID, KP, HID);
    gemm_kernel<true ><<<g12, blk, 0, stream>>>(h1, W2t, h2, b2, Bsz, HID, HID, HID);
    gemm_kernel<false><<<g3,  blk, 0, stream>>>(h2, W3t, kcur, b3, Bsz, KP, HID, CMB);
    comb_mid<<<gcomb, blk, 0, stream>>>(kcur, kacc, y, ain, h / 3.0f, h / 2.0f, 0);
    // k3
    gemm_kernel<true ><<<g12, blk, 0, stream>>>(ain, W1t, h1, b1, Bsz, HID, KP, HID);
    gemm_kernel<true ><<<g12, blk, 0, stream>>>(h1, W2t, h2, b2, Bsz, HID, HID, HID);
    gemm_kernel<false><<<g3,  blk, 0, stream>>>(h2, W3t, kcur, b3, Bsz, KP, HID, CMB);
    comb_mid<<<gcomb, blk, 0, stream>>>(kcur, kacc, y, ain, h / 3.0f, h, 0);
    // k4
    gemm_kernel<true ><<<g12, blk, 0, stream>>>(ain, W1t, h1, b1, Bsz, HID, KP, HID);
    gemm_kernel<true ><<<g12, blk, 0, stream>>>(h1, W2t, h2, b2, Bsz, HID, HID, HID);
    gemm_kernel<false><<<g3,  blk, 0, stream>>>(h2, W3t, kcur, b3, Bsz, KP, HID, CMB);
    comb_fin<<<gcomb, blk, 0, stream>>>(kcur, kacc, y, ain, h / 6.0f);
  }

  fin_k<<<(Bsz * OUT_D + 255) / 256, 256, 0, stream>>>(y, lstd, out);
}

// Round 2
// 7816.920 us; speedup vs baseline: 1.8035x; 1.8035x over previous
//
#include <hip/hip_runtime.h>
#include <stdint.h>

// Neural-ODE actor: y' = MLP(y), y(0)=[x|z], integrate t:0->1 with fixed RK4.
// NSTEP=16 (64 field evals). bf16 MFMA GEMMs, fp32 state + RK accumulation.
// R2: RK combine fused into L3 epilogue; L1 one-shot K=128 staging; NSTEP 32->16.

#define NSTEP 16

static constexpr int Bsz   = 16384;
static constexpr int IN_D  = 64;
static constexpr int OUT_D = 32;
static constexpr int CMB   = 96;   // IN_D + OUT_D
static constexpr int KP    = 128;  // padded CMB
static constexpr int HID   = 1024;

typedef __bf16 bf16x8 __attribute__((ext_vector_type(8)));
typedef float  f32x4  __attribute__((ext_vector_type(4)));

__device__ __forceinline__ uint16_t f2bf(float f) {
  uint32_t u = __float_as_uint(f);
  u += 0x7fffu + ((u >> 16) & 1u);   // RNE; inputs are finite
  return (uint16_t)(u >> 16);
}

// async global->LDS, 16B per lane. LDS dest is wave-uniform base + lane*16.
__device__ __forceinline__ void gl2lds16(const uint16_t* g, uint16_t* l) {
  typedef const __attribute__((address_space(1))) uint16_t gq_t;
  typedef __attribute__((address_space(3))) uint16_t ls_t;
  __builtin_amdgcn_global_load_lds((gq_t*)(uintptr_t)g, (ls_t*)(uintptr_t)l, 16, 0, 0);
}

// ---------------------------------------------------------------------------
// Generic 128x128-tile GEMM (used for L2): C = relu(A @ Bt^T + bias) -> bf16.
// A row-major [M][K], Bt row-major [N][K]. 4 waves, each 64x64 via 4x4 MFMAs.
// ---------------------------------------------------------------------------
__global__ __launch_bounds__(256) void gemm_relu(
    const uint16_t* __restrict__ A, const uint16_t* __restrict__ Bt,
    uint16_t* __restrict__ Cout, const float* __restrict__ bias,
    int N, int K)
{
  __shared__ uint16_t As[128 * 32];
  __shared__ uint16_t Bs[128 * 32];

  const int tid  = threadIdx.x;
  const int wave = tid >> 6;
  const int lane = tid & 63;
  const int m0 = blockIdx.y * 128;
  const int n0 = blockIdx.x * 128;
  const int wm = (wave & 1) * 64;
  const int wn = (wave >> 1) * 64;

  const int srow = wave * 32 + (lane >> 2);
  const int scol = (lane & 3) * 8;

  const uint16_t* gA0 = A  + (size_t)(m0 + srow) * K + scol;
  const uint16_t* gA1 = gA0 + (size_t)16 * K;
  const uint16_t* gB0 = Bt + (size_t)(n0 + srow) * K + scol;
  const uint16_t* gB1 = gB0 + (size_t)16 * K;

  uint16_t* lA0 = As + wave * 1024;
  uint16_t* lA1 = lA0 + 512;
  uint16_t* lB0 = Bs + wave * 1024;
  uint16_t* lB1 = lB0 + 512;

  f32x4 acc[4][4];
  const f32x4 z4 = {0.0f, 0.0f, 0.0f, 0.0f};
#pragma unroll
  for (int i = 0; i < 4; ++i)
#pragma unroll
    for (int j = 0; j < 4; ++j) acc[i][j] = z4;

  const int afo = (wm + (lane & 15)) * 32 + (lane >> 4) * 8;
  const int bfo = (wn + (lane & 15)) * 32 + (lane >> 4) * 8;

  for (int k0 = 0; k0 < K; k0 += 32) {
    gl2lds16(gA0 + k0, lA0);
    gl2lds16(gA1 + k0, lA1);
    gl2lds16(gB0 + k0, lB0);
    gl2lds16(gB1 + k0, lB1);
    __syncthreads();

    bf16x8 af[4], bf[4];
#pragma unroll
    for (int i = 0; i < 4; ++i) {
      af[i] = *(const bf16x8*)(As + afo + i * 16 * 32);
      bf[i] = *(const bf16x8*)(Bs + bfo + i * 16 * 32);
    }
#pragma unroll
    for (int i = 0; i < 4; ++i)
#pragma unroll
      for (int j = 0; j < 4; ++j)
        acc[i][j] = __builtin_amdgcn_mfma_f32_16x16x32_bf16(af[i], bf[j], acc[i][j], 0, 0, 0);
    __syncthreads();
  }

  const int colb = n0 + wn + (lane & 15);
  const int rowb = m0 + wm + ((lane >> 4) << 2);
#pragma unroll
  for (int j = 0; j < 4; ++j) {
    const int c = colb + j * 16;
    const float bv = bias[c];
#pragma unroll
    for (int i = 0; i < 4; ++i)
#pragma unroll
      for (int r = 0; r < 4; ++r) {
        const int row = rowb + i * 16 + r;
        float v = fmaxf(acc[i][j][r] + bv, 0.0f);
        Cout[(size_t)row * N + c] = f2bf(v);
      }
  }
}

// ---------------------------------------------------------------------------
// L1: K=128 fixed. Entire K resident in LDS (64 KB), ONE barrier, 64 MFMAs.
// C = relu(A @ Bt^T + bias) -> bf16, N = HID.
// ---------------------------------------------------------------------------
__global__ __launch_bounds__(256) void gemm_l1(
    const uint16_t* __restrict__ A, const uint16_t* __restrict__ Bt,
    uint16_t* __restrict__ Cout, const float* __restrict__ bias)
{
  __shared__ uint16_t As[4 * 128 * 32];   // 32 KB: 4 slabs of [128][32]
  __shared__ uint16_t Bs[4 * 128 * 32];   // 32 KB

  const int tid  = threadIdx.x;
  const int wave = tid >> 6;
  const int lane = tid & 63;
  const int m0 = blockIdx.y * 128;
  const int n0 = blockIdx.x * 128;
  const int wm = (wave & 1) * 64;
  const int wn = (wave >> 1) * 64;

  const int srow = wave * 32 + (lane >> 2);
  const int scol = (lane & 3) * 8;

  const uint16_t* gA0 = A  + (size_t)(m0 + srow) * KP + scol;
  const uint16_t* gA1 = gA0 + (size_t)16 * KP;
  const uint16_t* gB0 = Bt + (size_t)(n0 + srow) * KP + scol;
  const uint16_t* gB1 = gB0 + (size_t)16 * KP;

#pragma unroll
  for (int s = 0; s < 4; ++s) {
    uint16_t* lA0 = As + s * 4096 + wave * 1024;
    uint16_t* lB0 = Bs + s * 4096 + wave * 1024;
    gl2lds16(gA0 + s * 32, lA0);
    gl2lds16(gA1 + s * 32, lA0 + 512);
    gl2lds16(gB0 + s * 32, lB0);
    gl2lds16(gB1 + s * 32, lB0 + 512);
  }
  __syncthreads();

  f32x4 acc[4][4];
  const f32x4 z4 = {0.0f, 0.0f, 0.0f, 0.0f};
#pragma unroll
  for (int i = 0; i < 4; ++i)
#pragma unroll
    for (int j = 0; j < 4; ++j) acc[i][j] = z4;

  const int afo = (wm + (lane & 15)) * 32 + (lane >> 4) * 8;
  const int bfo = (wn + (lane & 15)) * 32 + (lane >> 4) * 8;

#pragma unroll
  for (int s = 0; s < 4; ++s) {
    bf16x8 af[4], bf[4];
#pragma unroll
    for (int i = 0; i < 4; ++i) {
      af[i] = *(const bf16x8*)(As + s * 4096 + afo + i * 16 * 32);
      bf[i] = *(const bf16x8*)(Bs + s * 4096 + bfo + i * 16 * 32);
    }
#pragma unroll
    for (int i = 0; i < 4; ++i)
#pragma unroll
      for (int j = 0; j < 4; ++j)
        acc[i][j] = __builtin_amdgcn_mfma_f32_16x16x32_bf16(af[i], bf[j], acc[i][j], 0, 0, 0);
  }

  const int colb = n0 + wn + (lane & 15);
  const int rowb = m0 + wm + ((lane >> 4) << 2);
#pragma unroll
  for (int j = 0; j < 4; ++j) {
    const int c = colb + j * 16;
    const float bv = bias[c];
#pragma unroll
    for (int i = 0; i < 4; ++i)
#pragma unroll
      for (int r = 0; r < 4; ++r) {
        const int row = rowb + i * 16 + r;
        float v = fmaxf(acc[i][j][r] + bv, 0.0f);
        Cout[(size_t)row * HID + c] = f2bf(v);
      }
  }
}

// ---------------------------------------------------------------------------
// L3 + fused RK combine. N = KP = 128 (one column tile) so each block owns
// complete rows of k. mode 0: kacc=wk*k, ain=bf16(y+cc*k)
//                     mode 1: kacc+=wk*k, ain=bf16(y+cc*k)
//                     mode 2: y+=kacc+wk*k, ain=bf16(y)
// ---------------------------------------------------------------------------
__global__ __launch_bounds__(256) void gemm_l3_comb(
    const uint16_t* __restrict__ A, const uint16_t* __restrict__ Bt,
    const float* __restrict__ bias,
    float* __restrict__ y, float* __restrict__ kacc, uint16_t* __restrict__ ain,
    float wk, float cc, int mode)
{
  __shared__ uint16_t As[128 * 32];
  __shared__ uint16_t Bs[128 * 32];

  const int tid  = threadIdx.x;
  const int wave = tid >> 6;
  const int lane = tid & 63;
  const int m0 = blockIdx.y * 128;
  const int wm = (wave & 1) * 64;
  const int wn = (wave >> 1) * 64;

  const int srow = wave * 32 + (lane >> 2);
  const int scol = (lane & 3) * 8;

  const uint16_t* gA0 = A  + (size_t)(m0 + srow) * HID + scol;
  const uint16_t* gA1 = gA0 + (size_t)16 * HID;
  const uint16_t* gB0 = Bt + (size_t)srow * HID + scol;
  const uint16_t* gB1 = gB0 + (size_t)16 * HID;

  uint16_t* lA0 = As + wave * 1024;
  uint16_t* lA1 = lA0 + 512;
  uint16_t* lB0 = Bs + wave * 1024;
  uint16_t* lB1 = lB0 + 512;

  f32x4 acc[4][4];
  const f32x4 z4 = {0.0f, 0.0f, 0.0f, 0.0f};
#pragma unroll
  for (int i = 0; i < 4; ++i)
#pragma unroll
    for (int j = 0; j < 4; ++j) acc[i][j] = z4;

  const int afo = (wm + (lane & 15)) * 32 + (lane >> 4) * 8;
  const int bfo = (wn + (lane & 15)) * 32 + (lane >> 4) * 8;

  for (int k0 = 0; k0 < HID; k0 += 32) {
    gl2lds16(gA0 + k0, lA0);
    gl2lds16(gA1 + k0, lA1);
    gl2lds16(gB0 + k0, lB0);
    gl2lds16(gB1 + k0, lB1);
    __syncthreads();

    bf16x8 af[4], bf[4];
#pragma unroll
    for (int i = 0; i < 4; ++i) {
      af[i] = *(const bf16x8*)(As + afo + i * 16 * 32);
      bf[i] = *(const bf16x8*)(Bs + bfo + i * 16 * 32);
    }
#pragma unroll
    for (int i = 0; i < 4; ++i)
#pragma unroll
      for (int j = 0; j < 4; ++j)
        acc[i][j] = __builtin_amdgcn_mfma_f32_16x16x32_bf16(af[i], bf[j], acc[i][j], 0, 0, 0);
    __syncthreads();
  }

  const int colb = wn + (lane & 15);
  const int rowb = m0 + wm + ((lane >> 4) << 2);
#pragma unroll
  for (int j = 0; j < 4; ++j) {
    const int c = colb + j * 16;
    if (c < CMB) {
      const float bv = bias[c];
#pragma unroll
      for (int i = 0; i < 4; ++i)
#pragma unroll
        for (int r = 0; r < 4; ++r) {
          const int row = rowb + i * 16 + r;
          const float kv = acc[i][j][r] + bv;
          const size_t yi = (size_t)row * CMB + c;
          const size_t ai = (size_t)row * KP + c;
          if (mode == 2) {
            float yn = y[yi] + kacc[yi] + wk * kv;
            y[yi] = yn;
            ain[ai] = f2bf(yn);
          } else {
            float ka = (mode == 0) ? (wk * kv) : (kacc[yi] + wk * kv);
            kacc[yi] = ka;
            ain[ai] = f2bf(y[yi] + cc * kv);
          }
        }
    }
  }
}

// Wt[n*Kp + k] = bf16(W[k*N + n]) with zero padding (K->Kp rows, N->Np cols).
__global__ void wt_kernel(const float* __restrict__ W, uint16_t* __restrict__ Wt,
                          int K, int N, int Kp, int Np)
{
  int idx = blockIdx.x * blockDim.x + threadIdx.x;
  if (idx >= Np * Kp) return;
  int n = idx / Kp, k = idx - n * Kp;
  float v = (k < K && n < N) ? W[(size_t)k * N + n] : 0.0f;
  Wt[idx] = f2bf(v);
}

// y(0) = [x|z]; ain = bf16(y) padded to KP with zeros.
__global__ void init_k(const float* __restrict__ x, const float* __restrict__ z,
                       float* __restrict__ y, uint16_t* __restrict__ ain)
{
  int i = blockIdx.x * blockDim.x + threadIdx.x;
  if (i >= Bsz * KP) return;
  int row = i >> 7, col = i & 127;
  float v = 0.0f;
  if (col < IN_D) v = x[(size_t)row * IN_D + col];
  else if (col < CMB) v = z[(size_t)row * OUT_D + (col - IN_D)];
  ain[i] = f2bf(v);
  if (col < CMB) y[(size_t)row * CMB + col] = v;
}

__global__ void fin_k(const float* __restrict__ y, const float* __restrict__ lstd,
                      float* __restrict__ out)
{
  int i = blockIdx.x * blockDim.x + threadIdx.x;
  if (i >= Bsz * OUT_D) return;
  int row = i >> 5, col = i & 31;
  out[i] = y[(size_t)row * CMB + IN_D + col];
  out[(size_t)Bsz * OUT_D + i] = expf(lstd[col]);
}

extern "C" void kernel_launch(void* const* d_in, const int* in_sizes, int n_in,
                              void* d_out, int out_size, void* d_ws, size_t ws_size,
                              hipStream_t stream) {
  const float* x    = (const float*)d_in[0];
  const float* z    = (const float*)d_in[1];
  const float* W1   = (const float*)d_in[2];
  const float* b1   = (const float*)d_in[3];
  const float* W2   = (const float*)d_in[4];
  const float* b2   = (const float*)d_in[5];
  const float* W3   = (const float*)d_in[6];
  const float* b3   = (const float*)d_in[7];
  const float* lstd = (const float*)d_in[8];
  float* out = (float*)d_out;

  char* p = (char*)d_ws;
  auto alloc = [&](size_t bytes) {
    char* r = p;
    p += (bytes + 255) & ~(size_t)255;
    return r;
  };
  uint16_t* W1t  = (uint16_t*)alloc((size_t)HID * KP * 2);
  uint16_t* W2t  = (uint16_t*)alloc((size_t)HID * HID * 2);
  uint16_t* W3t  = (uint16_t*)alloc((size_t)KP * HID * 2);
  float*    y    = (float*)alloc((size_t)Bsz * CMB * 4);
  float*    kacc = (float*)alloc((size_t)Bsz * CMB * 4);
  uint16_t* ain  = (uint16_t*)alloc((size_t)Bsz * KP * 2);
  uint16_t* h1   = (uint16_t*)alloc((size_t)Bsz * HID * 2);
  uint16_t* h2   = (uint16_t*)alloc((size_t)Bsz * HID * 2);
  (void)ws_size; (void)in_sizes; (void)n_in; (void)out_size;

  wt_kernel<<<(HID * KP + 255) / 256, 256, 0, stream>>>(W1, W1t, CMB, HID, KP, HID);
  wt_kernel<<<(HID * HID + 255) / 256, 256, 0, stream>>>(W2, W2t, HID, HID, HID, HID);
  wt_kernel<<<(KP * HID + 255) / 256, 256, 0, stream>>>(W3, W3t, HID, CMB, HID, KP);

  init_k<<<(Bsz * KP + 255) / 256, 256, 0, stream>>>(x, z, y, ain);

  const float h = 1.0f / (float)NSTEP;
  dim3 blk(256);
  dim3 g12(HID / 128, Bsz / 128);
  dim3 g3(1, Bsz / 128);

  for (int s = 0; s < NSTEP; ++s) {
    // k1
    gemm_l1  <<<g12, blk, 0, stream>>>(ain, W1t, h1, b1);
    gemm_relu<<<g12, blk, 0, stream>>>(h1, W2t, h2, b2, HID, HID);
    gemm_l3_comb<<<g3, blk, 0, stream>>>(h2, W3t, b3, y, kacc, ain, h / 6.0f, h / 2.0f, 0);
    // k2
    gemm_l1  <<<g12, blk, 0, stream>>>(ain, W1t, h1, b1);
    gemm_relu<<<g12, blk, 0, stream>>>(h1, W2t, h2, b2, HID, HID);
    gemm_l3_comb<<<g3, blk, 0, stream>>>(h2, W3t, b3, y, kacc, ain, h / 3.0f, h / 2.0f, 1);
    // k3
    gemm_l1  <<<g12, blk, 0, stream>>>(ain, W1t, h1, b1);
    gemm_relu<<<g12, blk, 0, stream>>>(h1, W2t, h2, b2, HID, HID);
    gemm_l3_comb<<<g3, blk, 0, stream>>>(h2, W3t, b3, y, kacc, ain, h / 3.0f, h, 1);
    // k4
    gemm_l1  <<<g12, blk, 0, stream>>>(ain, W1t, h1, b1);
    gemm_relu<<<g12, blk, 0, stream>>>(h1, W2t, h2, b2, HID, HID);
    gemm_l3_comb<<<g3, blk, 0, stream>>>(h2, W3t, b3, y, kacc, ain, h / 6.0f, 0.0f, 2);
  }

  fin_k<<<(Bsz * OUT_D + 255) / 256, 256, 0, stream>>>(y, lstd, out);
}